// Round 1
// baseline (123.518 us; speedup 1.0000x reference)
//
#include <hip/hip_runtime.h>
#include <hip/hip_bf16.h>

typedef __attribute__((ext_vector_type(8))) short short8;
typedef __attribute__((ext_vector_type(16))) float f32x16;

__device__ __forceinline__ unsigned short bfbits(float f) {
  return __builtin_bit_cast(unsigned short, __float2bfloat16(f));
}

__device__ __forceinline__ short8 lds_read16(const short* p, int byteOff) {
  return *reinterpret_cast<const short8*>(reinterpret_cast<const char*>(p) + byteOff);
}

#define MFMA(a, b, c) __builtin_amdgcn_mfma_f32_32x32x16_bf16((a), (b), (c), 0, 0, 0)

// x:[524288][64] f32 (flat reinterpret of [B,E,S,D]; expert = row>>16)
// w1:[8][64][256] f32, w2:[8][256][64] f32, out same shape as x.
__launch_bounds__(256, 2)
__global__ void ffn_fused(const float* __restrict__ x,
                          const float* __restrict__ w1,
                          const float* __restrict__ w2,
                          float* __restrict__ out) {
  // W1^T: [f=256][d=64] bf16, row pitch 128 B, byte ^= (f&7)<<4
  // W2^T: [d=64][f=256] bf16, row pitch 512 B, byte ^= (d&31)<<4
  __shared__ short w1t[256 * 64];
  __shared__ short w2t[64 * 256];

  const int tid  = threadIdx.x;
  const int lane = tid & 63;
  const int wv   = tid >> 6;   // wave 0..3
  const int m    = lane & 31;  // token-col / row-in-tile lane id
  const int g    = lane >> 5;  // half-wave

  const int e     = blockIdx.x >> 6;  // expert (64 blocks per expert)
  const int chunk = blockIdx.x & 63;

  const float* W1 = w1 + e * (64 * 256);
  const float* W2 = w2 + e * (256 * 64);

  // ---- stage W1^T (thread t owns column f=t; 16 d-quads) ----
  {
    const int f   = tid;
    const int swz = (f & 7) << 4;
#pragma unroll
    for (int i = 0; i < 16; ++i) {
      float a0 = W1[(4 * i + 0) * 256 + f];
      float a1 = W1[(4 * i + 1) * 256 + f];
      float a2 = W1[(4 * i + 2) * 256 + f];
      float a3 = W1[(4 * i + 3) * 256 + f];
      unsigned lo = (unsigned)bfbits(a0) | ((unsigned)bfbits(a1) << 16);
      unsigned hi = (unsigned)bfbits(a2) | ((unsigned)bfbits(a3) << 16);
      const int off = (f * 128 + i * 8) ^ swz;
      *reinterpret_cast<uint2*>(reinterpret_cast<char*>(w1t) + off) = make_uint2(lo, hi);
    }
  }
  // ---- stage W2^T (thread t owns column d=t&63; 16 f-quads) ----
  {
    const int d   = tid & 63;
    const int fb  = tid >> 6;
    const int swz = (d & 31) << 4;
#pragma unroll
    for (int i = 0; i < 16; ++i) {
      const int f4 = fb + 4 * i;
      const int f  = 4 * f4;
      float a0 = W2[(f + 0) * 64 + d];
      float a1 = W2[(f + 1) * 64 + d];
      float a2 = W2[(f + 2) * 64 + d];
      float a3 = W2[(f + 3) * 64 + d];
      unsigned lo = (unsigned)bfbits(a0) | ((unsigned)bfbits(a1) << 16);
      unsigned hi = (unsigned)bfbits(a2) | ((unsigned)bfbits(a3) << 16);
      const int off = (d * 512 + f4 * 8) ^ swz;
      *reinterpret_cast<uint2*>(reinterpret_cast<char*>(w2t) + off) = make_uint2(lo, hi);
    }
  }
  __syncthreads();  // only barrier in the kernel

  const long rowBase = (long)e * 65536 + (long)chunk * 1024;
  const int  swzm    = (m & 7) << 4;
  const int  swzd    = m << 4;  // (d&31)<<4, same for dt=0/1

  for (int it = 0; it < 4; ++it) {
    const long rb = rowBase + it * 256 + wv * 64;  // this wave's 64 rows

    // ---- load + convert x fragments (B-op of GEMM1: x^T), 256 B/lane ----
    short8 xf[2][4];
#pragma unroll
    for (int mt = 0; mt < 2; ++mt) {
#pragma unroll
      for (int ks = 0; ks < 4; ++ks) {
        const float* px = x + (rb + mt * 32 + m) * 64 + ks * 16 + g * 8;
        const float4 u0 = *reinterpret_cast<const float4*>(px);
        const float4 u1 = *reinterpret_cast<const float4*>(px + 4);
        short8 v;
        v[0] = (short)bfbits(u0.x); v[1] = (short)bfbits(u0.y);
        v[2] = (short)bfbits(u0.z); v[3] = (short)bfbits(u0.w);
        v[4] = (short)bfbits(u1.x); v[5] = (short)bfbits(u1.y);
        v[6] = (short)bfbits(u1.z); v[7] = (short)bfbits(u1.w);
        xf[mt][ks] = v;
      }
    }

    f32x16 o00, o01, o10, o11;  // out^T acc: o[dt][mt]
#pragma unroll
    for (int i = 0; i < 16; ++i) { o00[i] = 0.f; o01[i] = 0.f; o10[i] = 0.f; o11[i] = 0.f; }

#pragma unroll
    for (int ft = 0; ft < 8; ++ft) {
      // GEMM1: h^T tile [32f x 32m] = W1^T frag x x^T frag, K=64 (4 steps)
      short8 a[4];
#pragma unroll
      for (int ks = 0; ks < 4; ++ks)
        a[ks] = lds_read16(w1t, ((ft * 32 + m) * 128 + ks * 32 + g * 16) ^ swzm);

      f32x16 h0, h1;
#pragma unroll
      for (int i = 0; i < 16; ++i) { h0[i] = 0.f; h1[i] = 0.f; }
#pragma unroll
      for (int ks = 0; ks < 4; ++ks) {
        h0 = MFMA(a[ks], xf[0][ks], h0);
        h1 = MFMA(a[ks], xf[1][ks], h1);
      }

      // relu + pack to bf16 pairs: pk[2q+h] covers C regs 4q..4q+3
      unsigned pk0[8], pk1[8];
#pragma unroll
      for (int q = 0; q < 4; ++q) {
        pk0[2*q]   = (unsigned)bfbits(fmaxf(h0[4*q+0], 0.f)) | ((unsigned)bfbits(fmaxf(h0[4*q+1], 0.f)) << 16);
        pk0[2*q+1] = (unsigned)bfbits(fmaxf(h0[4*q+2], 0.f)) | ((unsigned)bfbits(fmaxf(h0[4*q+3], 0.f)) << 16);
        pk1[2*q]   = (unsigned)bfbits(fmaxf(h1[4*q+0], 0.f)) | ((unsigned)bfbits(fmaxf(h1[4*q+1], 0.f)) << 16);
        pk1[2*q+1] = (unsigned)bfbits(fmaxf(h1[4*q+2], 0.f)) | ((unsigned)bfbits(fmaxf(h1[4*q+3], 0.f)) << 16);
      }

      // GEMM2: out^T += W2^T frag x h^T frag; h^T B-frag built in-register:
      // consumer lane (m,g) needs source reg-quad q=(2*ks2+g)&3 from lanes m (j0..3)
      // and m+32 (j4..7) -> one cross-half __shfl_xor(32) pair per fragment.
#pragma unroll
      for (int sub = 0; sub < 2; ++sub) {
        const int ks2 = 2 * ft + sub;
        const short8 wA = lds_read16(w2t, (m * 512 + ks2 * 32 + g * 16) ^ swzd);
        const short8 wB = lds_read16(w2t, ((32 + m) * 512 + ks2 * 32 + g * 16) ^ swzd);
        const int qa = 2 * sub, qb = 2 * sub + 1;

        union { short8 v; unsigned u[4]; } b0, b1;
        {
          unsigned pa0 = pk0[2*qa], pa1 = pk0[2*qa+1];
          unsigned pb0 = pk0[2*qb], pb1 = pk0[2*qb+1];
          unsigned s0 = g ? pa0 : pb0, s1 = g ? pa1 : pb1;  // what partner needs
          unsigned k0 = g ? pb0 : pa0, k1 = g ? pb1 : pa1;  // what I keep
          unsigned r0 = __shfl_xor(s0, 32, 64);
          unsigned r1 = __shfl_xor(s1, 32, 64);
          b0.u[0] = g ? r0 : k0; b0.u[1] = g ? r1 : k1;
          b0.u[2] = g ? k0 : r0; b0.u[3] = g ? k1 : r1;
        }
        {
          unsigned pa0 = pk1[2*qa], pa1 = pk1[2*qa+1];
          unsigned pb0 = pk1[2*qb], pb1 = pk1[2*qb+1];
          unsigned s0 = g ? pa0 : pb0, s1 = g ? pa1 : pb1;
          unsigned k0 = g ? pb0 : pa0, k1 = g ? pb1 : pa1;
          unsigned r0 = __shfl_xor(s0, 32, 64);
          unsigned r1 = __shfl_xor(s1, 32, 64);
          b1.u[0] = g ? r0 : k0; b1.u[1] = g ? r1 : k1;
          b1.u[2] = g ? k0 : r0; b1.u[3] = g ? k1 : r1;
        }

        o00 = MFMA(wA, b0.v, o00);
        o10 = MFMA(wB, b0.v, o10);
        o01 = MFMA(wA, b1.v, o01);
        o11 = MFMA(wB, b1.v, o11);
      }
    }

    // ---- store out^T C-frags: 4 consecutive d per reg-quad -> float4 stores ----
#pragma unroll
    for (int mt = 0; mt < 2; ++mt) {
#pragma unroll
      for (int dt = 0; dt < 2; ++dt) {
        const f32x16& acc = (mt == 0) ? (dt == 0 ? o00 : o10) : (dt == 0 ? o01 : o11);
        float* po = out + (rb + mt * 32 + m) * 64 + dt * 32 + g * 4;
#pragma unroll
        for (int q = 0; q < 4; ++q) {
          float4 s;
          s.x = acc[4*q+0]; s.y = acc[4*q+1]; s.z = acc[4*q+2]; s.w = acc[4*q+3];
          *reinterpret_cast<float4*>(po + 8 * q) = s;  // d = dt*32 + 8q + 4g + 0..3
        }
      }
    }
  }
}

extern "C" void kernel_launch(void* const* d_in, const int* in_sizes, int n_in,
                              void* d_out, int out_size, void* d_ws, size_t ws_size,
                              hipStream_t stream) {
  const float* x  = (const float*)d_in[0];
  const float* w1 = (const float*)d_in[1];
  const float* w2 = (const float*)d_in[2];
  float* out = (float*)d_out;
  ffn_fused<<<dim3(512), dim3(256), 0, stream>>>(x, w1, w2, out);
}